// Round 10
// baseline (293.908 us; speedup 1.0000x reference)
//
#include <hip/hip_runtime.h>
#include <hip/hip_bf16.h>

#define U_N   2048
#define T_N   100000
#define D_N   256
#define TOPK  20
#define TP    100096          // tags padded to multiple of 128 (128*782)
#define NBX   782             // 128-col panels
#define NPX   98              // panels per XCD (last gets 96)
#define CAP   512
#define ZTH   2.9f

typedef __attribute__((ext_vector_type(8)))  int   i32x8;
typedef __attribute__((ext_vector_type(16))) float f32x16;

__device__ __forceinline__ void gload16(void* lds, const void* g) {
    __builtin_amdgcn_global_load_lds(
        (const __attribute__((address_space(1))) unsigned int*)g,
        (__attribute__((address_space(3))) unsigned int*)lds,
        16, 0, 0);
}

// fp32x4 -> 4 x fp8 e4m3 (OCP on gfx950), packed into one dword via HW cvt
__device__ __forceinline__ unsigned int f4_to_fp8x4(float4 v) {
    int w = __builtin_amdgcn_cvt_pk_fp8_f32(v.x, v.y, 0, false);
    w     = __builtin_amdgcn_cvt_pk_fp8_f32(v.z, v.w, w, true);
    return (unsigned int)w;
}

// ---- kernel 1: fused prep. blocks [0,2048): tags fp32->fp8 (+pad zero);
//      blocks [2048,2560): users fp32->fp8 + tau = ZTH*||u|| + cnt=0
__global__ void prep(const float* __restrict__ users, const float* __restrict__ tags,
                     unsigned char* __restrict__ usersF, unsigned char* __restrict__ tagsF,
                     float* __restrict__ tau, int* __restrict__ cnt) {
    int b = blockIdx.x;
    if (b < 2048) {
        long long stride = 2048LL * 256;
        long long total = (long long)TP * 64;      // float4 units per padded table
        for (long long i = (long long)b * 256 + threadIdx.x; i < total; i += stride) {
            int row = (int)(i >> 6);
            unsigned int w = 0;
            if (row < T_N) w = f4_to_fp8x4(((const float4*)tags)[i]);
            ((unsigned int*)tagsF)[i] = w;
        }
    } else {
        int wid = threadIdx.x >> 6, lane = threadIdx.x & 63;
        int u = (b - 2048) * 4 + wid;              // 512 blocks x 4 waves = 2048 users
        float4 v = ((const float4*)(users + (size_t)u * D_N))[lane];
        ((unsigned int*)(usersF + (size_t)u * D_N))[lane] = f4_to_fp8x4(v);
        float n2 = v.x*v.x + v.y*v.y + v.z*v.z + v.w*v.w;
        #pragma unroll
        for (int off = 32; off; off >>= 1) n2 += __shfl_down(n2, off);
        if (lane == 0) { tau[u] = ZTH * sqrtf(n2); cnt[u] = 0; }
    }
}

// ---- kernel 2: MX-fp8 full-K GEMM + filter.
// NOTE on __launch_bounds__: on this toolchain the 2nd arg behaves like CUDA's
// min-BLOCKS/CU (R9 evidence: (512,4)->VGPR cap 64 & spill, (512,2)->cap 128).
// (512,2): 2 blocks/CU (LDS-capped anyway) -> 4 waves/SIMD @ 128 VGPR.
// 512 blocks (2/CU), 512 thr = 8 waves (2 wave-rows x 4 wave-cols).
// Block = 128 users x 128-col panels. Per wave: 64 rows (2 x 32-row MFMA tiles)
// x 32 cols; A in regs a[2][4] i32x8 (64 VGPR), acc[2] f32x16 (32 VGPR) ~110 live.
// B streamed as 128-col x K=256 panels (32 KB) double-buffered in LDS,
// granule-swizzled (stored g = g ^ (col&15)) via pre-swizzled global source.
// One vmcnt(4)+barrier pair per panel; 8 MFMA (32x32x64) per wave per panel.
// XCD-sliced: XCD x owns bx [98x, 98x+98); 64 blocks/XCD = 16 by x 4 slices.
__global__ __launch_bounds__(512, 2) void gemm_filter(
        const unsigned char* __restrict__ usersF, const unsigned char* __restrict__ tagsF,
        const float* __restrict__ tau, int* __restrict__ cnt, int* __restrict__ list) {
    __shared__ unsigned char Bl[2][32768];   // 2 x 32 KB
    __shared__ float tauS[128];              // total 66 KB -> 2 blocks/CU

    int tid  = threadIdx.x;
    int lane = tid & 63;
    int wid  = tid >> 6;              // 0..7
    int wr   = wid >> 2;              // 0..1 -> 64 user rows each
    int wc   = wid & 3;               // 0..3 -> 32 tag cols each

    int blk  = blockIdx.x;
    int xcd  = blk & 7;
    int by   = (blk >> 3) & 15;       // 16 user groups of 128
    int sl   = (blk >> 7) & 3;        // 4 panel slices
    int xbeg = xcd * NPX;
    int xend = (xbeg + NPX < NBX) ? (xbeg + NPX) : NBX;
    int np   = (xend - xbeg - sl + 3) >> 2;   // 24 or 25 panels for this block
    int uBase = by * 128;

    // tau -> LDS (half of wave 0: 32 lanes x 16B = 128 floats)
    if (tid < 32) gload16(&tauS[tid * 4], tau + uBase + tid * 4);

    // ---- A into registers: row = uBase + wr*64 + mi*32 + (lane&31),
    //      k-bytes = ks*64 + (lane>>5)*32 .. +32   (fp8, K=256 total)
    i32x8 a[2][4];
    {
        const unsigned char* gA = usersF
            + (size_t)(uBase + wr * 64 + (lane & 31)) * D_N + (lane >> 5) * 32;
        #pragma unroll
        for (int mi = 0; mi < 2; ++mi)
            #pragma unroll
            for (int ks = 0; ks < 4; ++ks) {
                const int4* p = (const int4*)(gA + (size_t)mi * 32 * D_N + ks * 64);
                union { i32x8 v; int4 q[2]; } u;
                u.q[0] = p[0]; u.q[1] = p[1];
                a[mi][ks] = u.v;
            }
    }

    // staging: thread covers col (tid>>4)+it*32, dest granule tid&15 (linear);
    // source granule pre-swizzled: sgr = (tid&15) ^ (col&15), it-invariant.
    const int scol = tid >> 4;
    const int sgr  = (tid & 15) ^ (scol & 15);

    #define STAGE(bxv, b)                                                     \
        {   const unsigned char* gp = tagsF                                   \
                + (size_t)((bxv) * 128 + scol) * D_N + sgr * 16;              \
            unsigned char* dp = &Bl[b][tid * 16];                             \
            _Pragma("unroll")                                                 \
            for (int it = 0; it < 4; ++it)                                    \
                gload16(dp + it * 8192, gp + (size_t)it * 32 * D_N);          \
        }

    f32x16 acc[2] = {};
    // read-side constants: col cc, stored granule = g ^ (cc&15)
    int cc   = wc * 32 + (lane & 31);
    int cOff = cc * 256;
    int key  = cc & 15;
    int rbase = wr * 64 + 4 * (lane >> 5);   // + mi*32 + (i&3) + 8*(i>>2)

    int bx = xbeg + sl;
    STAGE(bx, 0);
    asm volatile("s_waitcnt vmcnt(0)" ::: "memory");   // A + tau + panel0
    __builtin_amdgcn_s_barrier();
    __builtin_amdgcn_sched_barrier(0);

    for (int p = 0; p < np; ++p) {
        if (p + 1 < np) {
            STAGE(bx + 4, (p + 1) & 1);
            asm volatile("s_waitcnt vmcnt(4)" ::: "memory");  // panel p landed
        } else {
            asm volatile("s_waitcnt vmcnt(0)" ::: "memory");
        }
        __builtin_amdgcn_s_barrier();
        __builtin_amdgcn_sched_barrier(0);

        const unsigned char* B0 = &Bl[p & 1][0];
        #pragma unroll
        for (int kf = 0; kf < 4; ++kf) {
            int g0 = kf * 4 + (lane >> 5) * 2;
            union { i32x8 v; int4 q[2]; } ub;
            ub.q[0] = *(const int4*)&B0[cOff + ((g0    ) ^ key) * 16];
            ub.q[1] = *(const int4*)&B0[cOff + ((g0 + 1) ^ key) * 16];
            i32x8 bfr = ub.v;
            __builtin_amdgcn_s_setprio(1);
            #pragma unroll
            for (int mi = 0; mi < 2; ++mi)
                acc[mi] = __builtin_amdgcn_mfma_scale_f32_32x32x64_f8f6f4(
                    a[mi][kf], bfr, acc[mi],
                    0, 0,                      // fp8 / fp8
                    0, 0x7F7F7F7F,             // opselA, scaleA (=1.0)
                    0, 0x7F7F7F7F);            // opselB, scaleB (=1.0)
            __builtin_amdgcn_s_setprio(0);
        }

        // per-panel epilogue: threshold filter (tau via half-wave-uniform
        // float4 broadcasts), then zero acc
        int col = bx * 128 + cc;
        #pragma unroll
        for (int mi = 0; mi < 2; ++mi) {
            #pragma unroll
            for (int g = 0; g < 4; ++g) {
                float4 t4 = *(const float4*)&tauS[rbase + mi * 32 + g * 8];
                #pragma unroll
                for (int j = 0; j < 4; ++j) {
                    float s = acc[mi][g * 4 + j];
                    if (col < T_N && s > (&t4.x)[j]) {
                        int u = uBase + rbase + mi * 32 + g * 8 + j;
                        int pos = atomicAdd(&cnt[u], 1);
                        if (pos < CAP) list[(size_t)u * CAP + pos] = col;
                    }
                    acc[mi][g * 4 + j] = 0.f;
                }
            }
        }
        __builtin_amdgcn_s_barrier();   // all waves done with Bl[p&1]
        bx += 4;
    }
    #undef STAGE
}

// ---- kernel 3: fp64 rescore + top-20. Scoring: 16-lane groups, coalesced
// gathers, shuffle reduce. Selection: wave 0 only, candidates in registers,
// 64-lane butterfly argmax, lower-index tie-break (matches lax.top_k).
__global__ __launch_bounds__(256) void rescore_select(
        const float* __restrict__ users, const float* __restrict__ tags,
        const int* __restrict__ cnt, const int* __restrict__ list, int* __restrict__ out) {
    int u = blockIdx.x, tid = threadIdx.x;
    __shared__ double sc[CAP];
    __shared__ int    tix[CAP];

    int lane16 = tid & 15, grp = tid >> 4;   // 16 groups x 16 lanes

    int c = cnt[u]; if (c > CAP) c = CAP;

    float uf[16];
    {
        const float4* uv = (const float4*)(users + (size_t)u * D_N + lane16 * 16);
        #pragma unroll
        for (int q = 0; q < 4; ++q) {
            float4 v = uv[q];
            uf[q*4+0] = v.x; uf[q*4+1] = v.y; uf[q*4+2] = v.z; uf[q*4+3] = v.w;
        }
    }

    for (int base = 0; base < c; base += 16) {
        int i = base + grp;
        double s = 0.0; int t = 0;
        if (i < c) {
            t = list[(size_t)u * CAP + i];
            const float4* tr = (const float4*)(tags + (size_t)t * D_N + lane16 * 16);
            #pragma unroll
            for (int q = 0; q < 4; ++q) {
                float4 bv = tr[q];
                s = fma((double)uf[q*4+0], (double)bv.x, s);
                s = fma((double)uf[q*4+1], (double)bv.y, s);
                s = fma((double)uf[q*4+2], (double)bv.z, s);
                s = fma((double)uf[q*4+3], (double)bv.w, s);
            }
        }
        #pragma unroll
        for (int m = 1; m < 16; m <<= 1) s += __shfl_xor(s, m);
        if (lane16 == 0 && i < c) { sc[i] = s; tix[i] = t; }
    }
    __syncthreads();

    if (tid < 64) {
        double s8[8]; int t8[8];
        #pragma unroll
        for (int j = 0; j < 8; ++j) {
            int i = tid + j * 64;
            if (i < c) { s8[j] = sc[i]; t8[j] = tix[i]; }
            else       { s8[j] = -1e300; t8[j] = 0x7fffffff; }
        }
        for (int r = 0; r < TOPK; ++r) {
            double bs = -1e299; int bt = 0x7fffffff; int bj = -1;
            #pragma unroll
            for (int j = 0; j < 8; ++j) {
                if (s8[j] > bs || (s8[j] == bs && t8[j] < bt)) { bs = s8[j]; bt = t8[j]; bj = j; }
            }
            #pragma unroll
            for (int m = 1; m < 64; m <<= 1) {
                double os = __shfl_xor(bs, m);
                int    ot = __shfl_xor(bt, m);
                if (os > bs || (os == bs && ot < bt)) { bs = os; bt = ot; }
            }
            if (bj >= 0 && s8[bj] == bs && t8[bj] == bt) s8[bj] = -1e300;  // owner invalidates
            if (tid == 0) out[(size_t)u * TOPK + r] = bt;
        }
    }
}

extern "C" void kernel_launch(void* const* d_in, const int* in_sizes, int n_in,
                              void* d_out, int out_size, void* d_ws, size_t ws_size,
                              hipStream_t stream) {
    const float* users = (const float*)d_in[0];
    const float* tags  = (const float*)d_in[1];
    int* out = (int*)d_out;

    char* ws = (char*)d_ws;
    size_t off = 0;
    unsigned char* tagsF  = (unsigned char*)(ws + off); off += (size_t)TP * D_N;   // 25.6 MB
    unsigned char* usersF = (unsigned char*)(ws + off); off += (size_t)U_N * D_N;  // 0.5 MB
    float* tau = (float*)(ws + off); off += (size_t)U_N * 4;
    int*   cnt = (int*)(ws + off);   off += (size_t)U_N * 4;
    int*   list = (int*)(ws + off);  off += (size_t)U_N * CAP * 4;                 // 4 MB

    prep<<<2560, 256, 0, stream>>>(users, tags, usersF, tagsF, tau, cnt);
    gemm_filter<<<512, 512, 0, stream>>>(usersF, tagsF, tau, cnt, list);
    rescore_select<<<U_N, 256, 0, stream>>>(users, tags, cnt, list, out);
}

// Round 11
// 271.408 us; speedup vs baseline: 1.0829x; 1.0829x over previous
//
#include <hip/hip_runtime.h>
#include <hip/hip_bf16.h>

#define U_N   2048
#define T_N   100000
#define D_N   256
#define TOPK  20
#define TP    100096          // tags padded to multiple of 128 (128*782)
#define NBX   782            // 128-col tag tiles
#define NBY   16             // 128-row user tiles
#define NWG   (NBX * NBY)    // 12512 = 8 * 1564
#define CAP   512
#define ZTH   2.9f

typedef __attribute__((ext_vector_type(8)))  int   i32x8;
typedef __attribute__((ext_vector_type(16))) float f32x16;

__device__ __forceinline__ void gload16(void* lds, const void* g) {
    __builtin_amdgcn_global_load_lds(
        (const __attribute__((address_space(1))) unsigned int*)g,
        (__attribute__((address_space(3))) unsigned int*)lds,
        16, 0, 0);
}

// fp32x4 -> 4 x fp8 e4m3 (OCP on gfx950), packed into one dword via HW cvt
__device__ __forceinline__ unsigned int f4_to_fp8x4(float4 v) {
    int w = __builtin_amdgcn_cvt_pk_fp8_f32(v.x, v.y, 0, false);
    w     = __builtin_amdgcn_cvt_pk_fp8_f32(v.z, v.w, w, true);
    return (unsigned int)w;
}

// ---- kernel 1: fused prep. blocks [0,2048): tags fp32->fp8 (+pad zero);
//      blocks [2048,2560): users NORMALIZED (u/||u||) fp32->fp8 + cnt=0.
//      Normalized users make the filter threshold a CONSTANT (ZTH), removing
//      all per-row tau traffic from the GEMM epilogue. fp8 noise ratio is
//      unchanged (floating point is scale-invariant; margin stays ~7 sigma).
__global__ void prep(const float* __restrict__ users, const float* __restrict__ tags,
                     unsigned char* __restrict__ usersF, unsigned char* __restrict__ tagsF,
                     int* __restrict__ cnt) {
    int b = blockIdx.x;
    if (b < 2048) {
        long long stride = 2048LL * 256;
        long long total = (long long)TP * 64;      // float4 units per padded table
        for (long long i = (long long)b * 256 + threadIdx.x; i < total; i += stride) {
            int row = (int)(i >> 6);
            unsigned int w = 0;
            if (row < T_N) w = f4_to_fp8x4(((const float4*)tags)[i]);
            ((unsigned int*)tagsF)[i] = w;
        }
    } else {
        int wid = threadIdx.x >> 6, lane = threadIdx.x & 63;
        int u = (b - 2048) * 4 + wid;              // 512 blocks x 4 waves = 2048 users
        float4 v = ((const float4*)(users + (size_t)u * D_N))[lane];
        float n2 = v.x*v.x + v.y*v.y + v.z*v.z + v.w*v.w;
        #pragma unroll
        for (int m = 1; m < 64; m <<= 1) n2 += __shfl_xor(n2, m);   // all lanes
        float inv = 1.0f / sqrtf(n2);
        float4 w; w.x = v.x*inv; w.y = v.y*inv; w.z = v.z*inv; w.w = v.w*inv;
        ((unsigned int*)(usersF + (size_t)u * D_N))[lane] = f4_to_fp8x4(w);
        if (lane == 0) cnt[u] = 0;
    }
}

// ---- kernel 2: ONE-SHOT fp8 GEMM block + filter. No K-loop, no dbuf, one
// barrier total; latency hiding comes from block-level TLP (12512 blocks,
// ~49 deep per CU, 2 resident via 64 KB LDS -- the R5 mechanism, m114).
// 256 thr = 4 waves (2x2), wave tile 64x64: acc[2][2] f32x16 (64 VGPR),
// live ~105 regs; __launch_bounds__(256,2) => cap 256 (2nd arg = min
// blocks/CU on this toolchain; R9/R10 evidence), no spill possible.
// A,B tiles granule-swizzled in LDS (stored g = g ^ (row&15)) via
// pre-swizzled global source (rule #21); reads apply same XOR (R10's
// measured-0-conflict pattern).
// XCD chunking: g = (l&7)*1564 + l>>3; within an XCD by varies fast =>
// 16 consecutive blocks share one B tile; per-XCD working set ~3.7 MB (L2).
__global__ __launch_bounds__(256, 2) void gemm_filter(
        const unsigned char* __restrict__ usersF, const unsigned char* __restrict__ tagsF,
        int* __restrict__ cnt, int* __restrict__ list) {
    __shared__ unsigned char Al[32768];   // 128 users x 256 B
    __shared__ unsigned char Bl[32768];   // 128 tags  x 256 B

    int tid  = threadIdx.x;
    int lane = tid & 63;
    int wid  = tid >> 6;              // 0..3
    int wrow = wid >> 1;              // 0..1 -> 64 user rows
    int wcol = wid & 1;               // 0..1 -> 64 tag cols

    int l  = blockIdx.x;
    int g  = (l & 7) * (NWG / 8) + (l >> 3);
    int by = g & (NBY - 1);
    int bx = g >> 4;
    int uBase = by * 128;

    // ---- stage A+B (64 KB): thread covers row (tid>>4)+it*16, dest granule
    // tid&15 (linear, gload_lds-legal); source granule pre-swizzled with
    // key row&15 = (tid>>4)&15 (it-invariant since step 16 rows).
    {
        int srow = tid >> 4;
        int sgr  = (tid & 15) ^ (srow & 15);
        const unsigned char* ga = usersF + (size_t)(uBase + srow) * D_N + sgr * 16;
        const unsigned char* gb = tagsF  + (size_t)(bx * 128 + srow) * D_N + sgr * 16;
        unsigned char* da = &Al[tid * 16];
        unsigned char* db = &Bl[tid * 16];
        #pragma unroll
        for (int it = 0; it < 8; ++it) {
            gload16(da + it * 4096, ga + (size_t)it * 16 * D_N);
            gload16(db + it * 4096, gb + (size_t)it * 16 * D_N);
        }
    }
    asm volatile("s_waitcnt vmcnt(0)" ::: "memory");
    __builtin_amdgcn_s_barrier();
    __builtin_amdgcn_sched_barrier(0);

    int half = lane >> 5;
    int rl   = lane & 31;
    int key  = lane & 15;             // (row&15) for every frag row below
    f32x16 acc[2][2] = {};

    #pragma unroll
    for (int kf = 0; kf < 4; ++kf) {
        int g0 = kf * 4 + half * 2;
        i32x8 bf[2], af[2];
        #pragma unroll
        for (int ci = 0; ci < 2; ++ci) {
            int r = (wcol * 64 + ci * 32 + rl) * 256;
            union { i32x8 v; int4 q[2]; } u;
            u.q[0] = *(const int4*)&Bl[r + ((g0    ) ^ key) * 16];
            u.q[1] = *(const int4*)&Bl[r + ((g0 + 1) ^ key) * 16];
            bf[ci] = u.v;
        }
        #pragma unroll
        for (int ri = 0; ri < 2; ++ri) {
            int r = (wrow * 64 + ri * 32 + rl) * 256;
            union { i32x8 v; int4 q[2]; } u;
            u.q[0] = *(const int4*)&Al[r + ((g0    ) ^ key) * 16];
            u.q[1] = *(const int4*)&Al[r + ((g0 + 1) ^ key) * 16];
            af[ri] = u.v;
        }
        __builtin_amdgcn_s_setprio(1);
        #pragma unroll
        for (int ri = 0; ri < 2; ++ri)
            #pragma unroll
            for (int ci = 0; ci < 2; ++ci)
                acc[ri][ci] = __builtin_amdgcn_mfma_scale_f32_32x32x64_f8f6f4(
                    af[ri], bf[ci], acc[ri][ci],
                    0, 0,                      // fp8 / fp8
                    0, 0x7F7F7F7F,             // opselA, scaleA (=1.0)
                    0, 0x7F7F7F7F);            // opselB, scaleB (=1.0)
        __builtin_amdgcn_s_setprio(0);
    }

    // ---- epilogue: constant-threshold filter (normalized users => tau = ZTH).
    // 32x32 C layout (m74, validated R8-R10): col = lane&31,
    // row = (e&3) + 8*(e>>2) + 4*(lane>>5). Pad tag rows are zero => never pass.
    int colB = bx * 128 + wcol * 64;
    int rowB = uBase + wrow * 64 + 4 * half;
    #pragma unroll
    for (int ri = 0; ri < 2; ++ri) {
        #pragma unroll
        for (int ci = 0; ci < 2; ++ci) {
            #pragma unroll
            for (int e = 0; e < 16; ++e) {
                float s = acc[ri][ci][e];
                if (s > ZTH) {
                    int u   = rowB + ri * 32 + (e & 3) + 8 * (e >> 2);
                    int col = colB + ci * 32 + rl;
                    int pos = atomicAdd(&cnt[u], 1);
                    if (pos < CAP) list[(size_t)u * CAP + pos] = col;
                }
            }
        }
    }
}

// ---- kernel 3: fp64 rescore + top-20. Scoring: 16-lane groups, coalesced
// gathers, shuffle reduce. Selection: wave 0 only, candidates in registers,
// 64-lane butterfly argmax, lower-index tie-break (matches lax.top_k).
__global__ __launch_bounds__(256) void rescore_select(
        const float* __restrict__ users, const float* __restrict__ tags,
        const int* __restrict__ cnt, const int* __restrict__ list, int* __restrict__ out) {
    int u = blockIdx.x, tid = threadIdx.x;
    __shared__ double sc[CAP];
    __shared__ int    tix[CAP];

    int lane16 = tid & 15, grp = tid >> 4;   // 16 groups x 16 lanes

    int c = cnt[u]; if (c > CAP) c = CAP;

    float uf[16];
    {
        const float4* uv = (const float4*)(users + (size_t)u * D_N + lane16 * 16);
        #pragma unroll
        for (int q = 0; q < 4; ++q) {
            float4 v = uv[q];
            uf[q*4+0] = v.x; uf[q*4+1] = v.y; uf[q*4+2] = v.z; uf[q*4+3] = v.w;
        }
    }

    for (int base = 0; base < c; base += 16) {
        int i = base + grp;
        double s = 0.0; int t = 0;
        if (i < c) {
            t = list[(size_t)u * CAP + i];
            const float4* tr = (const float4*)(tags + (size_t)t * D_N + lane16 * 16);
            #pragma unroll
            for (int q = 0; q < 4; ++q) {
                float4 bv = tr[q];
                s = fma((double)uf[q*4+0], (double)bv.x, s);
                s = fma((double)uf[q*4+1], (double)bv.y, s);
                s = fma((double)uf[q*4+2], (double)bv.z, s);
                s = fma((double)uf[q*4+3], (double)bv.w, s);
            }
        }
        #pragma unroll
        for (int m = 1; m < 16; m <<= 1) s += __shfl_xor(s, m);
        if (lane16 == 0 && i < c) { sc[i] = s; tix[i] = t; }
    }
    __syncthreads();

    if (tid < 64) {
        double s8[8]; int t8[8];
        #pragma unroll
        for (int j = 0; j < 8; ++j) {
            int i = tid + j * 64;
            if (i < c) { s8[j] = sc[i]; t8[j] = tix[i]; }
            else       { s8[j] = -1e300; t8[j] = 0x7fffffff; }
        }
        for (int r = 0; r < TOPK; ++r) {
            double bs = -1e299; int bt = 0x7fffffff; int bj = -1;
            #pragma unroll
            for (int j = 0; j < 8; ++j) {
                if (s8[j] > bs || (s8[j] == bs && t8[j] < bt)) { bs = s8[j]; bt = t8[j]; bj = j; }
            }
            #pragma unroll
            for (int m = 1; m < 64; m <<= 1) {
                double os = __shfl_xor(bs, m);
                int    ot = __shfl_xor(bt, m);
                if (os > bs || (os == bs && ot < bt)) { bs = os; bt = ot; }
            }
            if (bj >= 0 && s8[bj] == bs && t8[bj] == bt) s8[bj] = -1e300;  // owner invalidates
            if (tid == 0) out[(size_t)u * TOPK + r] = bt;
        }
    }
}

extern "C" void kernel_launch(void* const* d_in, const int* in_sizes, int n_in,
                              void* d_out, int out_size, void* d_ws, size_t ws_size,
                              hipStream_t stream) {
    const float* users = (const float*)d_in[0];
    const float* tags  = (const float*)d_in[1];
    int* out = (int*)d_out;

    char* ws = (char*)d_ws;
    size_t off = 0;
    unsigned char* tagsF  = (unsigned char*)(ws + off); off += (size_t)TP * D_N;   // 25.6 MB
    unsigned char* usersF = (unsigned char*)(ws + off); off += (size_t)U_N * D_N;  // 0.5 MB
    int*   cnt = (int*)(ws + off);   off += (size_t)U_N * 4;
    int*   list = (int*)(ws + off);  off += (size_t)U_N * CAP * 4;                 // 4 MB

    prep<<<2560, 256, 0, stream>>>(users, tags, usersF, tagsF, cnt);
    gemm_filter<<<NWG, 256, 0, stream>>>(usersF, tagsF, cnt, list);
    rescore_select<<<U_N, 256, 0, stream>>>(users, tags, cnt, list, out);
}